// Round 8
// baseline (205.422 us; speedup 1.0000x reference)
//
#include <hip/hip_runtime.h>
#include <hip/hip_bf16.h>

typedef unsigned short u16;
typedef unsigned int u32;

#define BATCH 4
#define NHIST 4
#define NPART 1000
#define NTOPK 10
#define NPT (BATCH*NPART)     // 4000 particles total
#define NET (NPT*NTOPK)       // 40000 receiver-slot capacity
#define NREG 64               // compaction regions (counter per 128B line)
#define EREG 640              // per-region edge capacity (16 blocks x 40 edges)
#define CAP (NREG*EREG)       // 40960 compacted-edge rows
#define NRT 10                // relation tiles per region (ceil(EREG/64), 64-row tiles)
#define NPB 63                // particle-encoder blocks (ceil(NPT/64))

typedef __bf16 b8v __attribute__((ext_vector_type(8)));
typedef float  f4v __attribute__((ext_vector_type(4)));

__device__ __forceinline__ float bf2f(u16 b){
    return __uint_as_float(((u32)b) << 16);
}
__device__ __forceinline__ u16 f2bf(float f){
    u32 u = __float_as_uint(f);
    u32 r = u + 0x7FFF + ((u >> 16) & 1);  // RNE
    return (u16)(r >> 16);
}
__device__ __forceinline__ float ldin(const void* p, size_t i, int isf32){
    return isf32 ? ((const float*)p)[i] : bf2f(((const u16*)p)[i]);
}
__device__ __forceinline__ void unp4(uint2 v, float* d){
    d[0]=bf2f((u16)v.x); d[1]=bf2f((u16)(v.x>>16));
    d[2]=bf2f((u16)v.y); d[3]=bf2f((u16)(v.y>>16));
}
__device__ __forceinline__ u32 pk2(float a, float b){
    return (u32)f2bf(a) | ((u32)f2bf(b) << 16);
}

// =============== setup: dtype-probe + weight swizzle + prep + topk+compact ===============
// grid 1090: blocks 0..73 weight swizzle, 74..89 prep, 90..1089 topk (wave = receiver).
__global__ __launch_bounds__(256) void k_setup(
    const void* __restrict__ a_hist, const void* __restrict__ s_hist,
    const void* __restrict__ s_delta,
    const void* w0, const void* w1, const void* w2, const void* w3,
    const void* w4, const void* w5, const void* w6, const void* w7,
    u16* __restrict__ wsw, int* __restrict__ dflag,
    float* __restrict__ s_cur, u16* __restrict__ pe_in,
    int* __restrict__ ecount, int* __restrict__ cidx, int* __restrict__ csend,
    u16* __restrict__ re_in)
{
    __shared__ u32 SMEM[8192];
    __shared__ int sdet;
    __shared__ int wcnt[4], wbase[4];
    int t = threadIdx.x;
    if (t == 0) sdet = 0;
    __syncthreads();
    {
        const u16* p = (const u16*)a_hist;
        int bad = 0;
        for (int i = t; i < 2000; i += 256) bad |= (p[i] >> 15) & 1;
        if (bad) atomicOr(&sdet, 1);
    }
    __syncthreads();
    int isf32 = sdet;
    int bid = blockIdx.x;

    if (bid < 74){
        const int nck[8] = {1,8,1,8,8,24,16,8};
        const int Ks[8]  = {16,256,5,256,256,768,512,256};
        const void* srcs[8] = {w0,w1,w2,w3,w4,w5,w6,w7};
        int wi = 0, c = bid;
        while (c >= nck[wi]){ c -= nck[wi]; wi++; }
        const void* src = srcs[wi];
        int K = Ks[wi];
        u16* stage = (u16*)SMEM;
        #pragma unroll 4
        for (int kk = 0; kk < 32; kk++){
            int k = c*32 + kk;
            float v = (k < K) ? ldin(src, (size_t)k*256 + t, isf32) : 0.f;
            int e = (t >> 4)*512 + ((kk >> 3)*16 + (t & 15))*8 + (kk & 7);
            stage[e] = f2bf(v);
        }
        __syncthreads();
        uint4* dstv = (uint4*)(wsw + (size_t)bid * 8192);
        const uint4* sv = (const uint4*)stage;
        dstv[t] = sv[t];
        dstv[t + 256] = sv[t + 256];
        dstv[t + 512] = sv[t + 512];
        dstv[t + 768] = sv[t + 768];
        return;
    }
    if (bid < 90){
        if (bid == 74 && t == 0) dflag[0] = isf32;
        int g = (bid - 74)*256 + t;
        if (g >= NPT) return;
        int b = g / NPART, i = g - b*NPART;
        #pragma unroll
        for (int d = 0; d < 3; d++)
            s_cur[g*3 + d] = ldin(s_hist, (size_t)((b*NHIST + NHIST-1)*NPART + i)*3 + d, isf32);
        #pragma unroll
        for (int h = 0; h < NHIST; h++){
            #pragma unroll
            for (int d = 0; d < 3; d++)
                pe_in[g*32 + h*3 + d] = f2bf(ldin(s_delta, (size_t)((b*NHIST + h)*NPART + i)*3 + d, isf32));
            pe_in[g*32 + 12 + h] = f2bf(ldin(a_hist, (b*NHIST + h)*NPART + i, isf32));
        }
        #pragma unroll
        for (int k = 16; k < 32; k++) pe_in[g*32 + k] = 0;
        return;
    }
    // ---- topk: 1000 blocks, WAVE = RECEIVER (4/block) ----
    float* sx = (float*)SMEM;
    float* sy = sx + 1000;
    float* sz = sx + 2000;
    float* sa = sx + 3000;
    u32* raw  = SMEM + 4096;
    u32* rawa = SMEM + 4096 + 3072;
    int tb = bid - 90;
    int b = tb / 250, r0 = (tb % 250) * 4;
    int wid = t >> 6, lane = t & 63;
    {
        int sbase = (b*NHIST + NHIST-1)*NPART*3;
        int abase = (b*NHIST + NHIST-1)*NPART;
        if (isf32){
            const uint4* ps = (const uint4*)((const float*)s_hist + sbase);
            for (int i = t; i < 750; i += 256) ((uint4*)raw)[i] = ps[i];
            const uint4* pa = (const uint4*)((const float*)a_hist + abase);
            if (t < 250) ((uint4*)rawa)[t] = pa[t];
        } else {
            const uint4* ps = (const uint4*)((const u16*)s_hist + sbase);
            for (int i = t; i < 375; i += 256) ((uint4*)raw)[i] = ps[i];
            const uint4* pa = (const uint4*)((const u16*)a_hist + abase);
            if (t < 125) ((uint4*)rawa)[t] = pa[t];
        }
    }
    __syncthreads();
    for (int j = t; j < NPART; j += 256){
        float vx, vy, vz, va;
        if (isf32){
            vx = ((const float*)raw)[j*3+0]; vy = ((const float*)raw)[j*3+1];
            vz = ((const float*)raw)[j*3+2]; va = ((const float*)rawa)[j];
        } else {
            vx = bf2f(((const u16*)raw)[j*3+0]); vy = bf2f(((const u16*)raw)[j*3+1]);
            vz = bf2f(((const u16*)raw)[j*3+2]); va = bf2f(((const u16*)rawa)[j]);
        }
        sx[j] = vx; sy[j] = vy; sz[j] = vz; sa[j] = va;
    }
    __syncthreads();
    int i = r0 + wid;
    float xi = sx[i], yi = sy[i], zi = sz[i];
    float ai = sa[i];
    bool tool_i = ai > 0.5f;
    float thr = tool_i ? -1.0f : 0.25f;

    float bd[NTOPK]; int bj[NTOPK];
    #pragma unroll
    for (int k = 0; k < NTOPK; k++){ bd[k] = 3.0e38f; bj[k] = 1 << 30; }
    for (int j = lane; j < NPART; j += 64){
        float dx = xi - sx[j], dy = yi - sy[j], dz = zi - sz[j];
        float d = dx*dx + dy*dy + dz*dz;
        if (d < thr && d < bd[NTOPK-1]){
            float v = d; int vj = j;
            #pragma unroll
            for (int k = 0; k < NTOPK; k++){
                bool sw = v < bd[k];
                float tv = bd[k]; int tj = bj[k];
                if (sw){ bd[k] = v; bj[k] = vj; v = tv; vj = tj; }
            }
        }
    }
    float myd = 3.0e38f; int myj = 0;
    #pragma unroll
    for (int r = 0; r < NTOPK; r++){
        float v = bd[0]; int vj = bj[0];
        #pragma unroll
        for (int s = 32; s > 0; s >>= 1){
            float ov = __shfl_xor(v, s);
            int   oj = __shfl_xor(vj, s);
            if (ov < v || (ov == v && oj < vj)){ v = ov; vj = oj; }
        }
        if (lane == r){ myd = v; myj = vj; }
        bool owner = (bd[0] == v) && (bj[0] == vj);
        if (owner){
            #pragma unroll
            for (int k = 0; k < NTOPK-1; k++){ bd[k] = bd[k+1]; bj[k] = bj[k+1]; }
            bd[NTOPK-1] = 3.0e38f; bj[NTOPK-1] = 1 << 30;
        }
    }
    bool fl = (lane < NTOPK) && (myd < 0.25f);
    int cnt = __popcll(__ballot(fl));
    if (lane == 0) wcnt[wid] = cnt;
    __syncthreads();
    if (t == 0){
        int c0 = wcnt[0], c1 = wcnt[1], c2 = wcnt[2], c3 = wcnt[3];
        int reg = tb & (NREG - 1);
        int bb = atomicAdd(&ecount[reg*32], c0 + c1 + c2 + c3) + reg*EREG;
        wbase[0] = bb; wbase[1] = bb + c0; wbase[2] = bb + c0 + c1; wbase[3] = bb + c0 + c1 + c2;
    }
    __syncthreads();
    int base = wbase[wid];
    if (lane < NTOPK){
        int gp = b*NPART + i;
        int ce = fl ? base + lane : -1;
        cidx[gp*NTOPK + lane] = ce;
        if (ce >= 0){
            int j = myj;
            csend[ce] = b*NPART + j;
            u32 q0 = (u32)f2bf(ai)        | ((u32)f2bf(sa[j])      << 16);
            u32 q1 = (u32)f2bf(xi - sx[j]) | ((u32)f2bf(yi - sy[j]) << 16);
            u32 q2 = (u32)f2bf(zi - sz[j]);
            uint4 v0 = {q0, q1, q2, 0};
            uint4 zz = {0, 0, 0, 0};
            uint4* rp = (uint4*)(re_in + (size_t)ce*32);
            rp[0] = v0; rp[1] = zz; rp[2] = zz; rp[3] = zz;
        }
    }
}

// =============== fused edge chain + particle encoder (+ Pr0/Ps0) ===============
// 64-row tiles x 512 threads: 8 waves, wave wn owns 2 coltiles (32 cols) and
// computes ALL 64 rows (acc[4][2]) -> W read exactly once per block, and
// per-row W L2 traffic HALVED vs the 32-row map (the k_edge regime per R7:
// L2-BW-bound on W). LDS 68 KB -> 2 blocks/CU, ~110 VGPR -> 4 waves/SIMD.
// Output bit-identical (same MFMA shapes/K-order/swizzles).
__global__ __launch_bounds__(512) void k_edge(
    const u16* __restrict__ re_in, const u16* __restrict__ pe_in,
    const u16* __restrict__ W0, const u16* __restrict__ W1,
    const u16* __restrict__ W2, const u16* __restrict__ W3,
    const u16* __restrict__ PW0, const u16* __restrict__ PW1,
    const u16* __restrict__ WrpB,
    const void* __restrict__ B0, const void* __restrict__ B1,
    const void* __restrict__ B2,
    const void* __restrict__ PB0, const void* __restrict__ PB1,
    const int* __restrict__ dflag, const int* __restrict__ ecount,
    u16* __restrict__ Eout, u16* __restrict__ penc,
    u16* __restrict__ Pr, u16* __restrict__ Ps)
{
    __shared__ u16 H1[64*256];
    __shared__ u16 H2[64*256];
    __shared__ u16 S[64*32];
    int t = threadIdx.x, lane = t & 63, wn = t >> 6;   // wn 0..7 = coltile pair
    int isf32 = dflag[0];
    int l15 = lane & 15, l4 = lane >> 4;

    f4v acc[4][2];
    b8v afr[4], bfA[2], bfB[2];
    auto zacc = [&](){
        #pragma unroll
        for (int rm = 0; rm < 4; rm++)
            #pragma unroll
            for (int j = 0; j < 2; j++) acc[rm][j] = {0.f,0.f,0.f,0.f};
    };
    auto rdWto = [&](b8v* dst, const u16* W, int kc){
        #pragma unroll
        for (int j = 0; j < 2; j++)
            dst[j] = *(const b8v*)(W + (size_t)kc*8192 + ((wn*2 + j)*64 + lane)*8);
    };
    auto domf = [&](b8v* wf){
        #pragma unroll
        for (int j = 0; j < 2; j++)
            #pragma unroll
            for (int rm = 0; rm < 4; rm++)
                acc[rm][j] = __builtin_amdgcn_mfma_f32_16x16x32_bf16(afr[rm], wf[j], acc[rm][j], 0, 0, 0);
    };
    auto rdA = [&](const u16* Hin, int kc){
        #pragma unroll
        for (int rm = 0; rm < 4; rm++){
            int R = rm*16 + l15;
            int up = (kc*4 + l4) ^ (R & 31);
            afr[rm] = *(const b8v*)&Hin[R*256 + up*8];
        }
    };
    // W double-buffered layer: prefetch kc+1 while MFMAing kc
    auto layer = [&](const u16* Hin, const u16* Wg){
        zacc();
        rdWto(bfA, Wg, 0);
        #pragma unroll
        for (int kc = 0; kc < 8; kc += 2){
            rdWto(bfB, Wg, kc + 1);
            rdA(Hin, kc); domf(bfA);
            if (kc + 2 < 8) rdWto(bfA, Wg, kc + 2);
            rdA(Hin, kc + 1); domf(bfB);
        }
    };
    auto epiLDS = [&](u16* Hout, const void* Wb){
        #pragma unroll
        for (int j = 0; j < 2; j++){
            int col = (wn*2 + j)*16 + l15;
            float bias = ldin(Wb, col, isf32);
            #pragma unroll
            for (int rm = 0; rm < 4; rm++){
                int rb = rm*16 + l4*4;
                #pragma unroll
                for (int r = 0; r < 4; r++){
                    float v = acc[rm][j][r] + bias;
                    v = v > 0.f ? v : 0.f;
                    int rr = rb + r;
                    int up = (col >> 3) ^ (rr & 31);
                    Hout[rr*256 + up*8 + (col & 7)] = f2bf(v);
                }
            }
        }
    };
    auto firstLayer = [&](const u16* Wg){
        zacc();
        rdWto(bfA, Wg, 0);
        #pragma unroll
        for (int rm = 0; rm < 4; rm++){
            int R = rm*16 + l15;
            int up = l4 ^ (R & 3);
            afr[rm] = *(const b8v*)&S[R*32 + up*8];
        }
        domf(bfA);
    };

    if (blockIdx.x >= NREG*NRT){
        // ---------- particle encoder + Pr0/Ps0 (64 rows/block, guarded) ----------
        int row0 = (blockIdx.x - NREG*NRT) * 64;
        if (t < 256){
            int row = t >> 2, q = t & 3;
            int rg = row0 + row; if (rg >= NPT) rg = NPT - 1;
            uint4 v = *(const uint4*)(pe_in + (size_t)rg*32 + q*8);
            int up = q ^ (row & 3);
            *(uint4*)&S[row*32 + up*8] = v;
        }
        __syncthreads();
        firstLayer(PW0);
        epiLDS(H1, PB0);
        __syncthreads();
        layer(H1, PW1);
        #pragma unroll
        for (int j = 0; j < 2; j++){
            int col = (wn*2 + j)*16 + l15;
            float bias = ldin(PB1, col, isf32);
            #pragma unroll
            for (int rm = 0; rm < 4; rm++){
                int rb = rm*16 + l4*4;
                #pragma unroll
                for (int r = 0; r < 4; r++){
                    int rr = rb + r;
                    float v = acc[rm][j][r] + bias;
                    v = v > 0.f ? v : 0.f;
                    if (row0 + rr < NPT)
                        penc[(size_t)(row0 + rr)*256 + col] = f2bf(v);
                    int up = (col >> 3) ^ (rr & 31);
                    H2[rr*256 + up*8 + (col & 7)] = f2bf(v);
                }
            }
        }
        __syncthreads();
        layer(H2, WrpB);
        #pragma unroll
        for (int j = 0; j < 2; j++){
            int col = (wn*2 + j)*16 + l15;
            #pragma unroll
            for (int rm = 0; rm < 4; rm++){
                int rb = row0 + rm*16 + l4*4;
                #pragma unroll
                for (int r = 0; r < 4; r++)
                    if (rb + r < NPT) Pr[(size_t)(rb + r)*256 + col] = f2bf(acc[rm][j][r]);
            }
        }
        layer(H2, WrpB + (size_t)8*8192);
        #pragma unroll
        for (int j = 0; j < 2; j++){
            int col = (wn*2 + j)*16 + l15;
            #pragma unroll
            for (int rm = 0; rm < 4; rm++){
                int rb = row0 + rm*16 + l4*4;
                #pragma unroll
                for (int r = 0; r < 4; r++)
                    if (rb + r < NPT) Ps[(size_t)(rb + r)*256 + col] = f2bf(acc[rm][j][r]);
            }
        }
        return;
    }

    // ---------- relation chain on 64-region compacted edges (64-row tiles) ----------
    int region = blockIdx.x / NRT;
    int local  = blockIdx.x - region*NRT;
    int ec = ecount[region*32];
    if (local*64 >= ec) return;
    int row0 = region*EREG + local*64;
    if (t < 256){
        int row = t >> 2, q = t & 3;
        int rg = row0 + row; if (rg >= CAP) rg = CAP - 1;
        uint4 v = *(const uint4*)(re_in + (size_t)rg*32 + q*8);
        int up = q ^ (row & 3);
        *(uint4*)&S[row*32 + up*8] = v;
    }
    __syncthreads();

    firstLayer(W0);
    epiLDS(H1, B0);
    __syncthreads();
    layer(H1, W1); epiLDS(H2, B1);
    __syncthreads();
    layer(H2, W2); epiLDS(H1, B2);
    __syncthreads();
    layer(H1, W3);
    #pragma unroll
    for (int j = 0; j < 2; j++){
        int col = (wn*2 + j)*16 + l15;
        #pragma unroll
        for (int rm = 0; rm < 4; rm++){
            int rb = row0 + rm*16 + l4*4;
            #pragma unroll
            for (int r = 0; r < 4; r++)
                Eout[(size_t)(rb + r)*256 + col] = f2bf(acc[rm][j][r]);
        }
    }
}

// =============== fused step: edge-agg gather + PP GEMM + {PrPs | predictor} ===============
// 250 blocks x 1024 threads (16 waves, 1 coltile each -> 4 waves/SIMD).
// 4-deep W prefetch ring; first 4 chunks issued BEFORE the gather.
// MODE 0: Pr/Ps = peff @ rp_w{recv,send}. MODE 1: predictor + out.
template<int MODE>
__global__ __launch_bounds__(1024) void k_step(
    const u16* __restrict__ penc,
    const u16* __restrict__ Erel,
    const int* __restrict__ cidx, const int* __restrict__ csend,
    const u16* __restrict__ PrIn, const u16* __restrict__ PsIn,
    const void* __restrict__ rp_b,
    const u16* __restrict__ Wpp, const void* __restrict__ Bpp,
    const u16* __restrict__ res, u16* __restrict__ peff_out,
    const u16* __restrict__ WrpB, u16* __restrict__ PrOut, u16* __restrict__ PsOut,
    const u16* __restrict__ Wpr0, const void* __restrict__ Bpr0,
    const void* __restrict__ w1, const void* __restrict__ b1,
    const float* __restrict__ s_cur, void* __restrict__ out,
    const int* __restrict__ dflag)
{
    constexpr int SMW = (MODE == 1) ? (12288 + 4224 + 1536 + 8) : 12288;
    __shared__ u16 SM[SMW];
    u16* pencT = SM;              // 16 x 256, H-swizzled
    u16* aggT  = SM + 4096;       // 16 x 256, H-swizzled
    u16* H     = SM + 8192;       // 16 x 256, H-swizzled
    int t = threadIdx.x, lane = t & 63, wv = t >> 6;   // wv 0..15 = coltile
    int l15 = lane & 15, l4 = lane >> 4;
    int row0 = blockIdx.x * 16;
    int isf32 = dflag[0];

    f4v acc;
    b8v af, bw[4];
    auto rdW1 = [&](b8v* dst, const u16* W, int kc){
        *dst = *(const b8v*)(W + (size_t)kc*8192 + (wv*64 + lane)*8);
    };
    auto rdH = [&](int kc){
        int up = (kc*4 + l4) ^ l15;
        af = *(const b8v*)&H[l15*256 + up*8];
    };
    auto rdA2 = [&](int kc){
        const u16* Hs = (kc < 8) ? pencT : aggT;
        int kk = kc & 7;
        int up = (kk*4 + l4) ^ l15;
        af = *(const b8v*)&Hs[l15*256 + up*8];
    };
    // K=256 layer from H, 4-deep W pipeline
    auto layer = [&](const u16* Wg){
        acc = {0.f,0.f,0.f,0.f};
        rdW1(&bw[0], Wg, 0); rdW1(&bw[1], Wg, 1);
        rdW1(&bw[2], Wg, 2); rdW1(&bw[3], Wg, 3);
        #pragma unroll
        for (int kc = 0; kc < 8; kc++){
            rdH(kc);
            acc = __builtin_amdgcn_mfma_f32_16x16x32_bf16(af, bw[kc & 3], acc, 0, 0, 0);
            if (kc + 4 < 8) rdW1(&bw[kc & 3], Wg, kc + 4);
        }
    };

    // issue first 4 PP W-chunks before the gather (hide W latency under gather)
    acc = {0.f,0.f,0.f,0.f};
    rdW1(&bw[0], Wpp, 0); rdW1(&bw[1], Wpp, 1);
    rdW1(&bw[2], Wpp, 2); rdW1(&bw[3], Wpp, 3);

    // ---- prologue: penc stage + fused edge aggregation into swizzled LDS ----
    // 16 rows x 64 col-groups of 4 cols -> all 1024 threads participate.
    {
        int grow = t >> 6;            // 0..15 (one wave per row)
        int cg = t & 63;              // col-group (4 cols)
        int c0g = cg * 4;
        int g = row0 + grow;
        int up = (c0g >> 3) ^ grow;
        uint2 pv = *(const uint2*)(penc + (size_t)g*256 + c0g);
        *(uint2*)&pencT[grow*256 + up*8 + (c0g & 7)] = pv;

        float prv[4];
        {
            uint2 p0 = *(const uint2*)(PrIn + (size_t)g*256 + c0g);
            unp4(p0, prv);
        }
        #pragma unroll
        for (int i = 0; i < 4; i++) prv[i] += ldin(rp_b, c0g + i, isf32);
        int cel[NTOPK], sdl[NTOPK];
        #pragma unroll
        for (int k = 0; k < NTOPK; k++){
            cel[k] = cidx[g*NTOPK + k];
            sdl[k] = (cel[k] >= 0) ? csend[cel[k]] : 0;
        }
        float sa[4];
        #pragma unroll
        for (int i = 0; i < 4; i++) sa[i] = 0.f;
        #pragma unroll
        for (int k = 0; k < NTOPK; k++){
            if (cel[k] >= 0){
                uint2 e0 = *(const uint2*)(Erel + (size_t)cel[k]*256 + c0g);
                uint2 q0 = *(const uint2*)(PsIn + (size_t)sdl[k]*256 + c0g);
                float ev[4], qv[4];
                unp4(e0, ev); unp4(q0, qv);
                #pragma unroll
                for (int i = 0; i < 4; i++){
                    float v = ev[i] + qv[i] + prv[i];
                    sa[i] += v > 0.f ? v : 0.f;
                }
            }
        }
        uint2 z;
        z.x = pk2(sa[0], sa[1]); z.y = pk2(sa[2], sa[3]);
        *(uint2*)&aggT[grow*256 + up*8 + (c0g & 7)] = z;
    }
    __syncthreads();

    // ---- PP GEMM: K=512, 4-deep W pipeline, no internal barriers ----
    #pragma unroll
    for (int kc = 0; kc < 16; kc++){
        rdA2(kc);
        acc = __builtin_amdgcn_mfma_f32_16x16x32_bf16(af, bw[kc & 3], acc, 0, 0, 0);
        if (kc + 4 < 16) rdW1(&bw[kc & 3], Wpp, kc + 4);
    }
    // ---- epilogue: bias + residual + relu -> H (LDS) [+ global peff] ----
    {
        int col = wv*16 + l15;
        float bias = ldin(Bpp, col, isf32);
        #pragma unroll
        for (int r = 0; r < 4; r++){
            int rr = l4*4 + r;
            int row = row0 + rr;
            float v = acc[r] + bias + bf2f(res[(size_t)row*256 + col]);
            v = v > 0.f ? v : 0.f;
            int up = (col >> 3) ^ rr;
            H[rr*256 + up*8 + (col & 7)] = f2bf(v);
            if (MODE == 0) peff_out[(size_t)row*256 + col] = f2bf(v);
        }
    }
    __syncthreads();
    if (MODE == 0){
        layer(WrpB);
        {
            int col = wv*16 + l15;
            #pragma unroll
            for (int r = 0; r < 4; r++)
                PrOut[(size_t)(row0 + l4*4 + r)*256 + col] = f2bf(acc[r]);
        }
        layer(WrpB + (size_t)8*8192);
        {
            int col = wv*16 + l15;
            #pragma unroll
            for (int r = 0; r < 4; r++)
                PsOut[(size_t)(row0 + l4*4 + r)*256 + col] = f2bf(acc[r]);
        }
    } else {
        u16* PH = SM + 12288;                     // 16 x 264
        float* sw1 = (float*)(SM + 12288 + 4224);
        float* sb1 = (float*)(SM + 12288 + 4224 + 1536);
        for (int i = t; i < 768; i += 1024) sw1[i] = ldin(w1, i, isf32);
        if (t < 3) sb1[t] = ldin(b1, t, isf32);
        layer(Wpr0);
        {
            int col = wv*16 + l15;
            float bias = ldin(Bpr0, col, isf32);
            #pragma unroll
            for (int r = 0; r < 4; r++){
                float v = acc[r] + bias;
                PH[(l4*4 + r)*264 + col] = f2bf(v > 0.f ? v : 0.f);
            }
        }
        __syncthreads();
        int row = t >> 3, dd = t & 7;
        if (t < 128 && dd < 3){
            int g = row0 + row;
            float s = sb1[dd] + s_cur[g*3 + dd];
            const u16* hr = &PH[row*264];
            #pragma unroll 8
            for (int k = 0; k < 256; k++)
                s += bf2f(hr[k]) * sw1[k*3 + dd];
            if (isf32) ((float*)out)[g*3 + dd] = s;
            else       ((u16*)out)[g*3 + dd]   = f2bf(s);
        }
    }
}

extern "C" void kernel_launch(void* const* d_in, const int* in_sizes, int n_in,
                              void* d_out, int out_size, void* d_ws, size_t ws_size,
                              hipStream_t stream) {
    const void* a_hist = d_in[0];
    const void* s_hist = d_in[1];
    const void* s_delta= d_in[2];
    const void* pe_w0 = d_in[3];  const void* pe_b0 = d_in[4];
    const void* pe_w1 = d_in[5];  const void* pe_b1 = d_in[6];
    const void* re_w0 = d_in[7];  const void* re_b0 = d_in[8];
    const void* re_w1 = d_in[9];  const void* re_b1 = d_in[10];
    const void* re_w2 = d_in[11]; const void* re_b2 = d_in[12];
    const void* rp_w  = d_in[13]; const void* rp_b  = d_in[14];
    const void* pp_w  = d_in[15]; const void* pp_b  = d_in[16];
    const void* pr_w0 = d_in[17]; const void* pr_b0 = d_in[18];
    const void* pr_w1 = d_in[19]; const void* pr_b1 = d_in[20];

    char* base = (char*)d_ws;
    size_t off = 0;
    auto alloc = [&](size_t bytes) -> char* {
        char* p = base + off;
        off += (bytes + 255) & ~(size_t)255;
        return p;
    };
    int*   dflag = (int*)  alloc(16);
    int*   ecount = (int*) alloc(NREG*32*4);        // 64 counters, 128B apart
    float* s_cur = (float*)alloc(NPT*3*4);
    int*   cidx  = (int*)  alloc(NET*4);
    int*   csend = (int*)  alloc(CAP*4);
    u16* pe_in = (u16*)alloc((size_t)NPT*32*2);
    u16* re_in = (u16*)alloc((size_t)CAP*32*2);
    u16* penc  = (u16*)alloc((size_t)NPT*256*2);
    u16* peffA = (u16*)alloc((size_t)NPT*256*2);
    u16* peffB = (u16*)alloc((size_t)NPT*256*2);
    u16* PrPs  = (u16*)alloc((size_t)4*NPT*256*2);  // PrA PsA PrB PsB
    u16* Erel  = (u16*)alloc((size_t)CAP*256*2);
    u16* wsw   = (u16*)alloc((size_t)74*8192*2);

    u16* sw_pe0 = wsw + (size_t) 0*8192;
    u16* sw_pe1 = wsw + (size_t) 1*8192;
    u16* sw_re0 = wsw + (size_t) 9*8192;
    u16* sw_re1 = wsw + (size_t)10*8192;
    u16* sw_re2 = wsw + (size_t)18*8192;
    u16* sw_rp  = wsw + (size_t)26*8192;   // 0..7 rel | 8..15 recv | 16..23 send
    u16* sw_pp  = wsw + (size_t)50*8192;
    u16* sw_pr0 = wsw + (size_t)66*8192;

    u16* PrA = PrPs;
    u16* PsA = PrPs + (size_t)NPT*256;
    u16* PrB = PrPs + (size_t)2*NPT*256;
    u16* PsB = PrPs + (size_t)3*NPT*256;
    u16* sw_rpB = sw_rp + (size_t)8*8192;  // recv bank (send bank at +8 chunks more)

    hipMemsetAsync(ecount, 0, NREG*32*4, stream);

    k_setup<<<1090, 256, 0, stream>>>(a_hist, s_hist, s_delta,
        pe_w0, pe_w1, re_w0, re_w1, re_w2, rp_w, pp_w, pr_w0,
        wsw, dflag, s_cur, pe_in, ecount, cidx, csend, re_in);

    k_edge<<<NREG*NRT + NPB, 512, 0, stream>>>(re_in, pe_in,
        sw_re0, sw_re1, sw_re2, sw_rp, sw_pe0, sw_pe1, sw_rpB,
        re_b0, re_b1, re_b2, pe_b0, pe_b1, dflag, ecount, Erel, penc, PrA, PsA);

    // step 1: gather(A) + PP + PrPs -> B
    k_step<0><<<250, 1024, 0, stream>>>(penc, Erel, cidx, csend, PrA, PsA, rp_b,
        sw_pp, pp_b, penc, peffA, sw_rpB, PrB, PsB,
        nullptr, nullptr, nullptr, nullptr, nullptr, nullptr, dflag);
    // step 2: gather(B) + PP + PrPs -> A
    k_step<0><<<250, 1024, 0, stream>>>(penc, Erel, cidx, csend, PrB, PsB, rp_b,
        sw_pp, pp_b, peffA, peffB, sw_rpB, PrA, PsA,
        nullptr, nullptr, nullptr, nullptr, nullptr, nullptr, dflag);
    // step 3: gather(A) + PP + predictor + output
    k_step<1><<<250, 1024, 0, stream>>>(penc, Erel, cidx, csend, PrA, PsA, rp_b,
        sw_pp, pp_b, peffB, nullptr, nullptr, nullptr, nullptr,
        sw_pr0, pr_b0, pr_w1, pr_b1, s_cur, (void*)d_out, dflag);
}

// Round 9
// 195.619 us; speedup vs baseline: 1.0501x; 1.0501x over previous
//
#include <hip/hip_runtime.h>
#include <hip/hip_bf16.h>

typedef unsigned short u16;
typedef unsigned int u32;

#define BATCH 4
#define NHIST 4
#define NPART 1000
#define NTOPK 10
#define NPT (BATCH*NPART)     // 4000 particles total
#define NET (NPT*NTOPK)       // 40000 receiver-slot capacity
#define NREG 64               // compaction regions (counter per 128B line)
#define EREG 640              // per-region edge capacity (16 blocks x 40 edges)
#define CAP (NREG*EREG)       // 40960 compacted-edge rows
#define NRT 20                // relation tiles per region (ceil(EREG/32), 32-row tiles)

typedef __bf16 b8v __attribute__((ext_vector_type(8)));
typedef float  f4v __attribute__((ext_vector_type(4)));

__device__ __forceinline__ float bf2f(u16 b){
    return __uint_as_float(((u32)b) << 16);
}
__device__ __forceinline__ u16 f2bf(float f){
    u32 u = __float_as_uint(f);
    u32 r = u + 0x7FFF + ((u >> 16) & 1);  // RNE
    return (u16)(r >> 16);
}
__device__ __forceinline__ float ldin(const void* p, size_t i, int isf32){
    return isf32 ? ((const float*)p)[i] : bf2f(((const u16*)p)[i]);
}
__device__ __forceinline__ void unp4(uint2 v, float* d){
    d[0]=bf2f((u16)v.x); d[1]=bf2f((u16)(v.x>>16));
    d[2]=bf2f((u16)v.y); d[3]=bf2f((u16)(v.y>>16));
}
__device__ __forceinline__ u32 pk2(float a, float b){
    return (u32)f2bf(a) | ((u32)f2bf(b) << 16);
}

// =============== setup: dtype-probe + weight swizzle + prep + topk+compact ===============
// grid 1090: blocks 0..73 weight swizzle, 74..89 prep, 90..1089 topk (wave = receiver).
__global__ __launch_bounds__(256) void k_setup(
    const void* __restrict__ a_hist, const void* __restrict__ s_hist,
    const void* __restrict__ s_delta,
    const void* w0, const void* w1, const void* w2, const void* w3,
    const void* w4, const void* w5, const void* w6, const void* w7,
    u16* __restrict__ wsw, int* __restrict__ dflag,
    float* __restrict__ s_cur, u16* __restrict__ pe_in,
    int* __restrict__ ecount, int* __restrict__ cidx, int* __restrict__ csend,
    u16* __restrict__ re_in)
{
    __shared__ u32 SMEM[8192];
    __shared__ int sdet;
    __shared__ int wcnt[4], wbase[4];
    int t = threadIdx.x;
    if (t == 0) sdet = 0;
    __syncthreads();
    {
        const u16* p = (const u16*)a_hist;
        int bad = 0;
        for (int i = t; i < 2000; i += 256) bad |= (p[i] >> 15) & 1;
        if (bad) atomicOr(&sdet, 1);
    }
    __syncthreads();
    int isf32 = sdet;
    int bid = blockIdx.x;

    if (bid < 74){
        const int nck[8] = {1,8,1,8,8,24,16,8};
        const int Ks[8]  = {16,256,5,256,256,768,512,256};
        const void* srcs[8] = {w0,w1,w2,w3,w4,w5,w6,w7};
        int wi = 0, c = bid;
        while (c >= nck[wi]){ c -= nck[wi]; wi++; }
        const void* src = srcs[wi];
        int K = Ks[wi];
        u16* stage = (u16*)SMEM;
        #pragma unroll 4
        for (int kk = 0; kk < 32; kk++){
            int k = c*32 + kk;
            float v = (k < K) ? ldin(src, (size_t)k*256 + t, isf32) : 0.f;
            int e = (t >> 4)*512 + ((kk >> 3)*16 + (t & 15))*8 + (kk & 7);
            stage[e] = f2bf(v);
        }
        __syncthreads();
        uint4* dstv = (uint4*)(wsw + (size_t)bid * 8192);
        const uint4* sv = (const uint4*)stage;
        dstv[t] = sv[t];
        dstv[t + 256] = sv[t + 256];
        dstv[t + 512] = sv[t + 512];
        dstv[t + 768] = sv[t + 768];
        return;
    }
    if (bid < 90){
        if (bid == 74 && t == 0) dflag[0] = isf32;
        int g = (bid - 74)*256 + t;
        if (g >= NPT) return;
        int b = g / NPART, i = g - b*NPART;
        #pragma unroll
        for (int d = 0; d < 3; d++)
            s_cur[g*3 + d] = ldin(s_hist, (size_t)((b*NHIST + NHIST-1)*NPART + i)*3 + d, isf32);
        #pragma unroll
        for (int h = 0; h < NHIST; h++){
            #pragma unroll
            for (int d = 0; d < 3; d++)
                pe_in[g*32 + h*3 + d] = f2bf(ldin(s_delta, (size_t)((b*NHIST + h)*NPART + i)*3 + d, isf32));
            pe_in[g*32 + 12 + h] = f2bf(ldin(a_hist, (b*NHIST + h)*NPART + i, isf32));
        }
        #pragma unroll
        for (int k = 16; k < 32; k++) pe_in[g*32 + k] = 0;
        return;
    }
    // ---- topk: 1000 blocks, WAVE = RECEIVER (4/block) ----
    float* sx = (float*)SMEM;
    float* sy = sx + 1000;
    float* sz = sx + 2000;
    float* sa = sx + 3000;
    u32* raw  = SMEM + 4096;
    u32* rawa = SMEM + 4096 + 3072;
    int tb = bid - 90;
    int b = tb / 250, r0 = (tb % 250) * 4;
    int wid = t >> 6, lane = t & 63;
    {
        int sbase = (b*NHIST + NHIST-1)*NPART*3;
        int abase = (b*NHIST + NHIST-1)*NPART;
        if (isf32){
            const uint4* ps = (const uint4*)((const float*)s_hist + sbase);
            for (int i = t; i < 750; i += 256) ((uint4*)raw)[i] = ps[i];
            const uint4* pa = (const uint4*)((const float*)a_hist + abase);
            if (t < 250) ((uint4*)rawa)[t] = pa[t];
        } else {
            const uint4* ps = (const uint4*)((const u16*)s_hist + sbase);
            for (int i = t; i < 375; i += 256) ((uint4*)raw)[i] = ps[i];
            const uint4* pa = (const uint4*)((const u16*)a_hist + abase);
            if (t < 125) ((uint4*)rawa)[t] = pa[t];
        }
    }
    __syncthreads();
    for (int j = t; j < NPART; j += 256){
        float vx, vy, vz, va;
        if (isf32){
            vx = ((const float*)raw)[j*3+0]; vy = ((const float*)raw)[j*3+1];
            vz = ((const float*)raw)[j*3+2]; va = ((const float*)rawa)[j];
        } else {
            vx = bf2f(((const u16*)raw)[j*3+0]); vy = bf2f(((const u16*)raw)[j*3+1]);
            vz = bf2f(((const u16*)raw)[j*3+2]); va = bf2f(((const u16*)rawa)[j]);
        }
        sx[j] = vx; sy[j] = vy; sz[j] = vz; sa[j] = va;
    }
    __syncthreads();
    int i = r0 + wid;
    float xi = sx[i], yi = sy[i], zi = sz[i];
    float ai = sa[i];
    bool tool_i = ai > 0.5f;
    float thr = tool_i ? -1.0f : 0.25f;

    float bd[NTOPK]; int bj[NTOPK];
    #pragma unroll
    for (int k = 0; k < NTOPK; k++){ bd[k] = 3.0e38f; bj[k] = 1 << 30; }
    for (int j = lane; j < NPART; j += 64){
        float dx = xi - sx[j], dy = yi - sy[j], dz = zi - sz[j];
        float d = dx*dx + dy*dy + dz*dz;
        if (d < thr && d < bd[NTOPK-1]){
            float v = d; int vj = j;
            #pragma unroll
            for (int k = 0; k < NTOPK; k++){
                bool sw = v < bd[k];
                float tv = bd[k]; int tj = bj[k];
                if (sw){ bd[k] = v; bj[k] = vj; v = tv; vj = tj; }
            }
        }
    }
    float myd = 3.0e38f; int myj = 0;
    #pragma unroll
    for (int r = 0; r < NTOPK; r++){
        float v = bd[0]; int vj = bj[0];
        #pragma unroll
        for (int s = 32; s > 0; s >>= 1){
            float ov = __shfl_xor(v, s);
            int   oj = __shfl_xor(vj, s);
            if (ov < v || (ov == v && oj < vj)){ v = ov; vj = oj; }
        }
        if (lane == r){ myd = v; myj = vj; }
        bool owner = (bd[0] == v) && (bj[0] == vj);
        if (owner){
            #pragma unroll
            for (int k = 0; k < NTOPK-1; k++){ bd[k] = bd[k+1]; bj[k] = bj[k+1]; }
            bd[NTOPK-1] = 3.0e38f; bj[NTOPK-1] = 1 << 30;
        }
    }
    bool fl = (lane < NTOPK) && (myd < 0.25f);
    int cnt = __popcll(__ballot(fl));
    if (lane == 0) wcnt[wid] = cnt;
    __syncthreads();
    if (t == 0){
        int c0 = wcnt[0], c1 = wcnt[1], c2 = wcnt[2], c3 = wcnt[3];
        int reg = tb & (NREG - 1);
        int bb = atomicAdd(&ecount[reg*32], c0 + c1 + c2 + c3) + reg*EREG;
        wbase[0] = bb; wbase[1] = bb + c0; wbase[2] = bb + c0 + c1; wbase[3] = bb + c0 + c1 + c2;
    }
    __syncthreads();
    int base = wbase[wid];
    if (lane < NTOPK){
        int gp = b*NPART + i;
        int ce = fl ? base + lane : -1;
        cidx[gp*NTOPK + lane] = ce;
        if (ce >= 0){
            int j = myj;
            csend[ce] = b*NPART + j;
            u32 q0 = (u32)f2bf(ai)        | ((u32)f2bf(sa[j])      << 16);
            u32 q1 = (u32)f2bf(xi - sx[j]) | ((u32)f2bf(yi - sy[j]) << 16);
            u32 q2 = (u32)f2bf(zi - sz[j]);
            uint4 v0 = {q0, q1, q2, 0};
            uint4 zz = {0, 0, 0, 0};
            uint4* rp = (uint4*)(re_in + (size_t)ce*32);
            rp[0] = v0; rp[1] = zz; rp[2] = zz; rp[3] = zz;
        }
    }
}

// =============== fused edge chain + particle encoder (+ Pr0/Ps0) ===============
// 32-row tiles x 256 threads, R7 wave map: wave wn (0..3) owns 4 coltiles (64
// cols) and computes BOTH 16-row halves (acc[2][4]) -> each layer's W is read
// exactly ONCE per block. 34 KB LDS -> 4 blocks/CU (best of the tile family:
// R8's 64-row variant regressed on occupancy/barrier width).
__global__ __launch_bounds__(256) void k_edge(
    const u16* __restrict__ re_in, const u16* __restrict__ pe_in,
    const u16* __restrict__ W0, const u16* __restrict__ W1,
    const u16* __restrict__ W2, const u16* __restrict__ W3,
    const u16* __restrict__ PW0, const u16* __restrict__ PW1,
    const u16* __restrict__ WrpB,
    const void* __restrict__ B0, const void* __restrict__ B1,
    const void* __restrict__ B2,
    const void* __restrict__ PB0, const void* __restrict__ PB1,
    const int* __restrict__ dflag, const int* __restrict__ ecount,
    u16* __restrict__ Eout, u16* __restrict__ penc,
    u16* __restrict__ Pr, u16* __restrict__ Ps)
{
    __shared__ u16 H1[32*256];
    __shared__ u16 H2[32*256];
    __shared__ u16 S[32*32];
    int t = threadIdx.x, lane = t & 63, wn = t >> 6;   // wn 0..3 = coltile group
    int isf32 = dflag[0];
    int l15 = lane & 15, l4 = lane >> 4;

    f4v acc[2][4];
    b8v afr[2], bfA[4], bfB[4];
    auto zacc = [&](){
        #pragma unroll
        for (int rm = 0; rm < 2; rm++)
            #pragma unroll
            for (int j = 0; j < 4; j++) acc[rm][j] = {0.f,0.f,0.f,0.f};
    };
    auto rdWto = [&](b8v* dst, const u16* W, int kc){
        #pragma unroll
        for (int j = 0; j < 4; j++)
            dst[j] = *(const b8v*)(W + (size_t)kc*8192 + ((wn*4 + j)*64 + lane)*8);
    };
    auto domf = [&](b8v* wf){
        #pragma unroll
        for (int j = 0; j < 4; j++)
            #pragma unroll
            for (int rm = 0; rm < 2; rm++)
                acc[rm][j] = __builtin_amdgcn_mfma_f32_16x16x32_bf16(afr[rm], wf[j], acc[rm][j], 0, 0, 0);
    };
    auto rdA = [&](const u16* Hin, int kc){
        #pragma unroll
        for (int rm = 0; rm < 2; rm++){
            int R = rm*16 + l15;
            int up = (kc*4 + l4) ^ (R & 31);
            afr[rm] = *(const b8v*)&Hin[R*256 + up*8];
        }
    };
    // W double-buffered layer: prefetch kc+1 while MFMAing kc
    auto layer = [&](const u16* Hin, const u16* Wg){
        zacc();
        rdWto(bfA, Wg, 0);
        #pragma unroll
        for (int kc = 0; kc < 8; kc += 2){
            rdWto(bfB, Wg, kc + 1);
            rdA(Hin, kc); domf(bfA);
            if (kc + 2 < 8) rdWto(bfA, Wg, kc + 2);
            rdA(Hin, kc + 1); domf(bfB);
        }
    };
    auto epiLDS = [&](u16* Hout, const void* Wb){
        #pragma unroll
        for (int j = 0; j < 4; j++){
            int col = (wn*4 + j)*16 + l15;
            float bias = ldin(Wb, col, isf32);
            #pragma unroll
            for (int rm = 0; rm < 2; rm++){
                int rb = rm*16 + l4*4;
                #pragma unroll
                for (int r = 0; r < 4; r++){
                    float v = acc[rm][j][r] + bias;
                    v = v > 0.f ? v : 0.f;
                    int rr = rb + r;
                    int up = (col >> 3) ^ (rr & 31);
                    Hout[rr*256 + up*8 + (col & 7)] = f2bf(v);
                }
            }
        }
    };
    auto stLin = [&](u16* C, int row0){
        #pragma unroll
        for (int j = 0; j < 4; j++){
            int col = (wn*4 + j)*16 + l15;
            #pragma unroll
            for (int rm = 0; rm < 2; rm++){
                int rb = row0 + rm*16 + l4*4;
                #pragma unroll
                for (int r = 0; r < 4; r++)
                    C[(size_t)(rb + r)*256 + col] = f2bf(acc[rm][j][r]);
            }
        }
    };
    auto firstLayer = [&](const u16* Wg){
        zacc();
        rdWto(bfA, Wg, 0);
        #pragma unroll
        for (int rm = 0; rm < 2; rm++){
            int R = rm*16 + l15;
            int up = l4 ^ (R & 3);
            afr[rm] = *(const b8v*)&S[R*32 + up*8];
        }
        domf(bfA);
    };

    if (blockIdx.x >= NREG*NRT){
        // ---------- particle encoder + Pr0/Ps0 ----------
        int row0 = (blockIdx.x - NREG*NRT) * 32;
        if (t < 128){
            int row = t >> 2, q = t & 3;
            int rg = row0 + row;
            uint4 v = *(const uint4*)(pe_in + (size_t)rg*32 + q*8);
            int up = q ^ (row & 3);
            *(uint4*)&S[row*32 + up*8] = v;
        }
        __syncthreads();
        firstLayer(PW0);
        epiLDS(H1, PB0);
        __syncthreads();
        layer(H1, PW1);
        #pragma unroll
        for (int j = 0; j < 4; j++){
            int col = (wn*4 + j)*16 + l15;
            float bias = ldin(PB1, col, isf32);
            #pragma unroll
            for (int rm = 0; rm < 2; rm++){
                int rb = rm*16 + l4*4;
                #pragma unroll
                for (int r = 0; r < 4; r++){
                    int rr = rb + r;
                    float v = acc[rm][j][r] + bias;
                    v = v > 0.f ? v : 0.f;
                    penc[(size_t)(row0 + rr)*256 + col] = f2bf(v);
                    int up = (col >> 3) ^ (rr & 31);
                    H2[rr*256 + up*8 + (col & 7)] = f2bf(v);
                }
            }
        }
        __syncthreads();
        layer(H2, WrpB);                      stLin(Pr, row0);
        layer(H2, WrpB + (size_t)8*8192);     stLin(Ps, row0);
        return;
    }

    // ---------- relation chain on 64-region compacted edges (32-row tiles) ----------
    int region = blockIdx.x / NRT;
    int local  = blockIdx.x - region*NRT;
    int ec = ecount[region*32];
    if (local*32 >= ec) return;
    int row0 = region*EREG + local*32;
    if (t < 128){
        int row = t >> 2, q = t & 3;
        int rg = row0 + row; if (rg >= CAP) rg = CAP - 1;
        uint4 v = *(const uint4*)(re_in + (size_t)rg*32 + q*8);
        int up = q ^ (row & 3);
        *(uint4*)&S[row*32 + up*8] = v;
    }
    __syncthreads();

    firstLayer(W0);
    epiLDS(H1, B0);
    __syncthreads();
    layer(H1, W1); epiLDS(H2, B1);
    __syncthreads();
    layer(H2, W2); epiLDS(H1, B2);
    __syncthreads();
    layer(H1, W3);
    stLin(Eout, row0);
}

// =============== fused step: edge-agg gather + PP GEMM + {PrPs | predictor} ===============
// 250 blocks x 1024 threads (16 waves, 1 coltile each -> 4 waves/SIMD).
// 4-deep W prefetch ring; first 4 chunks issued BEFORE the gather.
// RESLDS: residual is penc (step 1) -> read it from the already-staged pencT
// LDS tile (identical swizzle as H) instead of 2 MB global re-read.
// MODE 0: Pr/Ps = peff @ rp_w{recv,send}. MODE 1: predictor + out.
template<int MODE, int RESLDS>
__global__ __launch_bounds__(1024) void k_step(
    const u16* __restrict__ penc,
    const u16* __restrict__ Erel,
    const int* __restrict__ cidx, const int* __restrict__ csend,
    const u16* __restrict__ PrIn, const u16* __restrict__ PsIn,
    const void* __restrict__ rp_b,
    const u16* __restrict__ Wpp, const void* __restrict__ Bpp,
    const u16* __restrict__ res, u16* __restrict__ peff_out,
    const u16* __restrict__ WrpB, u16* __restrict__ PrOut, u16* __restrict__ PsOut,
    const u16* __restrict__ Wpr0, const void* __restrict__ Bpr0,
    const void* __restrict__ w1, const void* __restrict__ b1,
    const float* __restrict__ s_cur, void* __restrict__ out,
    const int* __restrict__ dflag)
{
    constexpr int SMW = (MODE == 1) ? (12288 + 4224 + 1536 + 8) : 12288;
    __shared__ u16 SM[SMW];
    u16* pencT = SM;              // 16 x 256, H-swizzled
    u16* aggT  = SM + 4096;       // 16 x 256, H-swizzled
    u16* H     = SM + 8192;       // 16 x 256, H-swizzled
    int t = threadIdx.x, lane = t & 63, wv = t >> 6;   // wv 0..15 = coltile
    int l15 = lane & 15, l4 = lane >> 4;
    int row0 = blockIdx.x * 16;
    int isf32 = dflag[0];

    f4v acc;
    b8v af, bw[4];
    auto rdW1 = [&](b8v* dst, const u16* W, int kc){
        *dst = *(const b8v*)(W + (size_t)kc*8192 + (wv*64 + lane)*8);
    };
    auto rdH = [&](int kc){
        int up = (kc*4 + l4) ^ l15;
        af = *(const b8v*)&H[l15*256 + up*8];
    };
    auto rdA2 = [&](int kc){
        const u16* Hs = (kc < 8) ? pencT : aggT;
        int kk = kc & 7;
        int up = (kk*4 + l4) ^ l15;
        af = *(const b8v*)&Hs[l15*256 + up*8];
    };
    // K=256 layer from H, 4-deep W pipeline
    auto layer = [&](const u16* Wg){
        acc = {0.f,0.f,0.f,0.f};
        rdW1(&bw[0], Wg, 0); rdW1(&bw[1], Wg, 1);
        rdW1(&bw[2], Wg, 2); rdW1(&bw[3], Wg, 3);
        #pragma unroll
        for (int kc = 0; kc < 8; kc++){
            rdH(kc);
            acc = __builtin_amdgcn_mfma_f32_16x16x32_bf16(af, bw[kc & 3], acc, 0, 0, 0);
            if (kc + 4 < 8) rdW1(&bw[kc & 3], Wg, kc + 4);
        }
    };

    // issue first 4 PP W-chunks before the gather (hide W latency under gather)
    acc = {0.f,0.f,0.f,0.f};
    rdW1(&bw[0], Wpp, 0); rdW1(&bw[1], Wpp, 1);
    rdW1(&bw[2], Wpp, 2); rdW1(&bw[3], Wpp, 3);

    // ---- prologue: penc stage + fused edge aggregation into swizzled LDS ----
    // 16 rows x 64 col-groups of 4 cols -> all 1024 threads participate.
    {
        int grow = t >> 6;            // 0..15 (one wave per row)
        int cg = t & 63;              // col-group (4 cols)
        int c0g = cg * 4;
        int g = row0 + grow;
        int up = (c0g >> 3) ^ grow;
        uint2 pv = *(const uint2*)(penc + (size_t)g*256 + c0g);
        *(uint2*)&pencT[grow*256 + up*8 + (c0g & 7)] = pv;

        float prv[4];
        {
            uint2 p0 = *(const uint2*)(PrIn + (size_t)g*256 + c0g);
            unp4(p0, prv);
        }
        #pragma unroll
        for (int i = 0; i < 4; i++) prv[i] += ldin(rp_b, c0g + i, isf32);
        int cel[NTOPK], sdl[NTOPK];
        #pragma unroll
        for (int k = 0; k < NTOPK; k++){
            cel[k] = cidx[g*NTOPK + k];
            sdl[k] = (cel[k] >= 0) ? csend[cel[k]] : 0;
        }
        float sa[4];
        #pragma unroll
        for (int i = 0; i < 4; i++) sa[i] = 0.f;
        #pragma unroll
        for (int k = 0; k < NTOPK; k++){
            if (cel[k] >= 0){
                uint2 e0 = *(const uint2*)(Erel + (size_t)cel[k]*256 + c0g);
                uint2 q0 = *(const uint2*)(PsIn + (size_t)sdl[k]*256 + c0g);
                float ev[4], qv[4];
                unp4(e0, ev); unp4(q0, qv);
                #pragma unroll
                for (int i = 0; i < 4; i++){
                    float v = ev[i] + qv[i] + prv[i];
                    sa[i] += v > 0.f ? v : 0.f;
                }
            }
        }
        uint2 z;
        z.x = pk2(sa[0], sa[1]); z.y = pk2(sa[2], sa[3]);
        *(uint2*)&aggT[grow*256 + up*8 + (c0g & 7)] = z;
    }
    __syncthreads();

    // ---- PP GEMM: K=512, 4-deep W pipeline, no internal barriers ----
    #pragma unroll
    for (int kc = 0; kc < 16; kc++){
        rdA2(kc);
        acc = __builtin_amdgcn_mfma_f32_16x16x32_bf16(af, bw[kc & 3], acc, 0, 0, 0);
        if (kc + 4 < 16) rdW1(&bw[kc & 3], Wpp, kc + 4);
    }
    // ---- epilogue: bias + residual + relu -> H (LDS) [+ global peff] ----
    {
        int col = wv*16 + l15;
        float bias = ldin(Bpp, col, isf32);
        #pragma unroll
        for (int r = 0; r < 4; r++){
            int rr = l4*4 + r;
            int row = row0 + rr;
            int e = rr*256 + ((col >> 3) ^ rr)*8 + (col & 7);
            float resv = RESLDS ? bf2f(pencT[e])
                                : bf2f(res[(size_t)row*256 + col]);
            float v = acc[r] + bias + resv;
            v = v > 0.f ? v : 0.f;
            H[e] = f2bf(v);
            if (MODE == 0) peff_out[(size_t)row*256 + col] = f2bf(v);
        }
    }
    __syncthreads();
    if (MODE == 0){
        layer(WrpB);
        {
            int col = wv*16 + l15;
            #pragma unroll
            for (int r = 0; r < 4; r++)
                PrOut[(size_t)(row0 + l4*4 + r)*256 + col] = f2bf(acc[r]);
        }
        layer(WrpB + (size_t)8*8192);
        {
            int col = wv*16 + l15;
            #pragma unroll
            for (int r = 0; r < 4; r++)
                PsOut[(size_t)(row0 + l4*4 + r)*256 + col] = f2bf(acc[r]);
        }
    } else {
        u16* PH = SM + 12288;                     // 16 x 264
        float* sw1 = (float*)(SM + 12288 + 4224);
        float* sb1 = (float*)(SM + 12288 + 4224 + 1536);
        for (int i = t; i < 768; i += 1024) sw1[i] = ldin(w1, i, isf32);
        if (t < 3) sb1[t] = ldin(b1, t, isf32);
        layer(Wpr0);
        {
            int col = wv*16 + l15;
            float bias = ldin(Bpr0, col, isf32);
            #pragma unroll
            for (int r = 0; r < 4; r++){
                float v = acc[r] + bias;
                PH[(l4*4 + r)*264 + col] = f2bf(v > 0.f ? v : 0.f);
            }
        }
        __syncthreads();
        int row = t >> 3, dd = t & 7;
        if (t < 128 && dd < 3){
            int g = row0 + row;
            float s = sb1[dd] + s_cur[g*3 + dd];
            const u16* hr = &PH[row*264];
            #pragma unroll 8
            for (int k = 0; k < 256; k++)
                s += bf2f(hr[k]) * sw1[k*3 + dd];
            if (isf32) ((float*)out)[g*3 + dd] = s;
            else       ((u16*)out)[g*3 + dd]   = f2bf(s);
        }
    }
}

extern "C" void kernel_launch(void* const* d_in, const int* in_sizes, int n_in,
                              void* d_out, int out_size, void* d_ws, size_t ws_size,
                              hipStream_t stream) {
    const void* a_hist = d_in[0];
    const void* s_hist = d_in[1];
    const void* s_delta= d_in[2];
    const void* pe_w0 = d_in[3];  const void* pe_b0 = d_in[4];
    const void* pe_w1 = d_in[5];  const void* pe_b1 = d_in[6];
    const void* re_w0 = d_in[7];  const void* re_b0 = d_in[8];
    const void* re_w1 = d_in[9];  const void* re_b1 = d_in[10];
    const void* re_w2 = d_in[11]; const void* re_b2 = d_in[12];
    const void* rp_w  = d_in[13]; const void* rp_b  = d_in[14];
    const void* pp_w  = d_in[15]; const void* pp_b  = d_in[16];
    const void* pr_w0 = d_in[17]; const void* pr_b0 = d_in[18];
    const void* pr_w1 = d_in[19]; const void* pr_b1 = d_in[20];

    char* base = (char*)d_ws;
    size_t off = 0;
    auto alloc = [&](size_t bytes) -> char* {
        char* p = base + off;
        off += (bytes + 255) & ~(size_t)255;
        return p;
    };
    int*   dflag = (int*)  alloc(16);
    int*   ecount = (int*) alloc(NREG*32*4);        // 64 counters, 128B apart
    float* s_cur = (float*)alloc(NPT*3*4);
    int*   cidx  = (int*)  alloc(NET*4);
    int*   csend = (int*)  alloc(CAP*4);
    u16* pe_in = (u16*)alloc((size_t)NPT*32*2);
    u16* re_in = (u16*)alloc((size_t)CAP*32*2);
    u16* penc  = (u16*)alloc((size_t)NPT*256*2);
    u16* peffA = (u16*)alloc((size_t)NPT*256*2);
    u16* peffB = (u16*)alloc((size_t)NPT*256*2);
    u16* PrPs  = (u16*)alloc((size_t)4*NPT*256*2);  // PrA PsA PrB PsB
    u16* Erel  = (u16*)alloc((size_t)CAP*256*2);
    u16* wsw   = (u16*)alloc((size_t)74*8192*2);

    u16* sw_pe0 = wsw + (size_t) 0*8192;
    u16* sw_pe1 = wsw + (size_t) 1*8192;
    u16* sw_re0 = wsw + (size_t) 9*8192;
    u16* sw_re1 = wsw + (size_t)10*8192;
    u16* sw_re2 = wsw + (size_t)18*8192;
    u16* sw_rp  = wsw + (size_t)26*8192;   // 0..7 rel | 8..15 recv | 16..23 send
    u16* sw_pp  = wsw + (size_t)50*8192;
    u16* sw_pr0 = wsw + (size_t)66*8192;

    u16* PrA = PrPs;
    u16* PsA = PrPs + (size_t)NPT*256;
    u16* PrB = PrPs + (size_t)2*NPT*256;
    u16* PsB = PrPs + (size_t)3*NPT*256;
    u16* sw_rpB = sw_rp + (size_t)8*8192;  // recv bank (send bank at +8 chunks more)

    hipMemsetAsync(ecount, 0, NREG*32*4, stream);

    k_setup<<<1090, 256, 0, stream>>>(a_hist, s_hist, s_delta,
        pe_w0, pe_w1, re_w0, re_w1, re_w2, rp_w, pp_w, pr_w0,
        wsw, dflag, s_cur, pe_in, ecount, cidx, csend, re_in);

    k_edge<<<NREG*NRT + 125, 256, 0, stream>>>(re_in, pe_in,
        sw_re0, sw_re1, sw_re2, sw_rp, sw_pe0, sw_pe1, sw_rpB,
        re_b0, re_b1, re_b2, pe_b0, pe_b1, dflag, ecount, Erel, penc, PrA, PsA);

    // step 1: gather(A) + PP + PrPs -> B   (residual = penc, read from LDS tile)
    k_step<0,1><<<250, 1024, 0, stream>>>(penc, Erel, cidx, csend, PrA, PsA, rp_b,
        sw_pp, pp_b, penc, peffA, sw_rpB, PrB, PsB,
        nullptr, nullptr, nullptr, nullptr, nullptr, nullptr, dflag);
    // step 2: gather(B) + PP + PrPs -> A
    k_step<0,0><<<250, 1024, 0, stream>>>(penc, Erel, cidx, csend, PrB, PsB, rp_b,
        sw_pp, pp_b, peffA, peffB, sw_rpB, PrA, PsA,
        nullptr, nullptr, nullptr, nullptr, nullptr, nullptr, dflag);
    // step 3: gather(A) + PP + predictor + output
    k_step<1,0><<<250, 1024, 0, stream>>>(penc, Erel, cidx, csend, PrA, PsA, rp_b,
        sw_pp, pp_b, peffB, nullptr, nullptr, nullptr, nullptr,
        sw_pr0, pr_b0, pr_w1, pr_b1, s_cur, (void*)d_out, dflag);
}